// Round 7
// baseline (150.347 us; speedup 1.0000x reference)
//
#include <hip/hip_runtime.h>
#include <hip/hip_cooperative_groups.h>
#include <math.h>

namespace cg = cooperative_groups;

#define HH 96
#define WW 96
#define CC 64
#define BB 4
#define PLANE (HH * WW)          // 9216
#define NPLANES (BB * CC)        // 256
#define NPC (BB * PLANE)         // 36864 per-channel count
#define TILE 32
#define TPL 3
#define HALO 34
#define HALO_N (HALO * HALO)     // 1156
#define BLOCK 256

typedef _Float16 h2v __attribute__((ext_vector_type(2)));

static __device__ __forceinline__ float dot2h(unsigned a, unsigned b, float c) {
#if __has_builtin(__builtin_amdgcn_fdot2)
    return __builtin_amdgcn_fdot2(__builtin_bit_cast(h2v, a),
                                  __builtin_bit_cast(h2v, b), c, false);
#else
    h2v x = __builtin_bit_cast(h2v, a);
    h2v y = __builtin_bit_cast(h2v, b);
    return c + (float)x[0] * (float)y[0] + (float)x[1] * (float)y[1];
#endif
}

static __device__ __forceinline__ unsigned pk16(float a, float b) {
    return __builtin_bit_cast(unsigned, __builtin_amdgcn_cvt_pkrtz(a, b));
}

// Round-3 verified compute structure (32-row strips, 3-tile sweep, conflict-
// free b128 phase C, NO min-waves launch bound -> no spills). COOP=1 adds a
// cooperative grid sync so BN+ReLU is applied from registers (y written once,
// no stage2). COOP=0 is the safe two-kernel fallback path.
// Partial layout: part[c*12 + b*3 + strip].

template <int COOP>
__global__ __launch_bounds__(BLOCK) void kconv_main(
    const float* __restrict__ x,
    const float* __restrict__ base_w,
    const float* __restrict__ spline_w,   // (9,8)
    const float* __restrict__ spline_s,   // (9,)
    const float* __restrict__ gamma,
    const float* __restrict__ beta,
    float* __restrict__ y,
    float2* __restrict__ part)
{
    __shared__ uint4  s_n[HALO_N];        // packed fp16 N8 per halo cell
    __shared__ float  s_sl[HALO_N];       // silu per halo cell
    __shared__ unsigned s_wp[36];
    __shared__ float  s_bw[9];
    __shared__ float2 red[4];
    __shared__ float2 sb;

    const int tid = threadIdx.x;

    if (tid < 36) {
        const int j = tid >> 2;
        const int k = tid & 3;
        const float sc = spline_s[j];
        s_wp[tid] = pk16(spline_w[j * 8 + 2 * k] * sc,
                         spline_w[j * 8 + 2 * k + 1] * sc);
    }
    if (tid < 9) s_bw[tid] = base_w[tid];

    const int plane = blockIdx.y;
    const int c = plane & (CC - 1);
    const int b = plane >> 6;
    const int h0 = blockIdx.x * TILE;
    const float* xp = x + (size_t)plane * PLANE;

    int hy[5], hx[5];
#pragma unroll
    for (int s = 0; s < 5; ++s) {
        const int i = tid + s * BLOCK;
        const int r = i / HALO;
        hy[s] = r;
        hx[s] = i - r * HALO;
    }

    const int tx  = tid & 31;
    const int ty4 = (tid >> 5) * 4;

    float acc[TPL][4] = {};

    unsigned wp[36];
    float bw[9];

    for (int wt = 0; wt < TPL; ++wt) {
        const int w0 = wt * TILE;

        // ---- phase A: prefetch halo (independent loads) ----
        float v[5];
#pragma unroll
        for (int s = 0; s < 5; ++s) {
            const int gh = h0 + hy[s] - 1;
            const int gw = w0 + hx[s] - 1;
            const bool ok = (tid + s * BLOCK < HALO_N) &&
                            gh >= 0 && gh < HH && gw >= 0 && gw < WW;
            v[s] = ok ? xp[gh * WW + gw] : 0.0f;
        }

        __syncthreads();   // wt=0: weight staging; wt>0: prev phase-C done

        if (wt == 0) {
#pragma unroll
            for (int q = 0; q < 36; ++q)
                wp[q] = __builtin_amdgcn_readfirstlane(s_wp[q]);
#pragma unroll
            for (int q = 0; q < 9; ++q)
                bw[q] = __int_as_float(__builtin_amdgcn_readfirstlane(__float_as_int(s_bw[q])));
        }

        // ---- phase B: silu + shifted fp16 basis vector per halo cell ----
#pragma unroll
        for (int s = 0; s < 5; ++s) {
            const int i = tid + s * BLOCK;
            if (i >= HALO_N) break;
            const float vv = v[s];
            const float e  = __expf(-vv);
            const float sl = vv * __builtin_amdgcn_rcpf(1.0f + e);

            const float sp = fmaf(vv, 2.5f, 2.5f);   // sigma - 3
            const float tf = floorf(sp);
            const float u  = sp - tf;
            const int   t  = (int)tf;
            const int   m  = t >> 1;
            const bool  odd = (t & 1) != 0;

            const float w1m = 1.0f - u;
            const float u2 = u * u;
            const float u3 = u2 * u;
            const float B0 = w1m * w1m * (w1m * (1.0f / 6.0f));
            const float B3 = u2 * (u * (1.0f / 6.0f));
            const float B1 = fmaf(-u2, 1.0f, fmaf(u3, 0.5f, 2.0f / 3.0f));
            const float B2 = 1.0f - B0 - B1 - B3;

            const unsigned h01 = pk16(B0, B1);
            const unsigned h23 = pk16(B2, B3);

            unsigned n[4];
            unsigned a_prev;
            {
                const int k0 = -1 - m;
                a_prev = (k0 == 0) ? h01 : ((k0 == 1) ? h23 : 0u);
            }
#pragma unroll
            for (int d = 0; d < 4; ++d) {
                const int k0 = d - m;
                const unsigned a_cur = (k0 == 0) ? h01 : ((k0 == 1) ? h23 : 0u);
                const unsigned sh = __builtin_amdgcn_alignbit(a_cur, a_prev, 16);
                n[d] = odd ? sh : a_cur;
                a_prev = a_cur;
            }
            s_n[i]  = make_uint4(n[0], n[1], n[2], n[3]);
            s_sl[i] = sl;
        }
        __syncthreads();

        // ---- phase C: 4 vertical pixels/thread, roll over 6 halo rows ----
#pragma unroll
        for (int r = 0; r < 6; ++r) {
            const int base = (ty4 + r) * HALO + tx;
            uint4 cn[3];
            float cs[3];
#pragma unroll
            for (int dw = 0; dw < 3; ++dw) {
                cn[dw] = s_n[base + dw];
                cs[dw] = s_sl[base + dw];
            }
#pragma unroll
            for (int k = 0; k < 4; ++k) {
                const int dh = r - k;
                if (dh >= 0 && dh < 3) {
                    float a = acc[wt][k];
#pragma unroll
                    for (int dw = 0; dw < 3; ++dw) {
                        const int j = dh * 3 + dw;
                        a = dot2h(cn[dw].x, wp[j * 4 + 0], a);
                        a = dot2h(cn[dw].y, wp[j * 4 + 1], a);
                        a = dot2h(cn[dw].z, wp[j * 4 + 2], a);
                        a = dot2h(cn[dw].w, wp[j * 4 + 3], a);
                        a = fmaf(bw[j], cs[dw], a);
                    }
                    acc[wt][k] = a;
                }
            }
        }
    }

    // block-wide (sum, sumsq) -> one partial per block
    float lsum = 0.0f, lsq = 0.0f;
#pragma unroll
    for (int wt = 0; wt < TPL; ++wt)
#pragma unroll
        for (int k = 0; k < 4; ++k) {
            lsum += acc[wt][k];
            lsq = fmaf(acc[wt][k], acc[wt][k], lsq);
        }
#pragma unroll
    for (int off = 32; off; off >>= 1) {
        lsum += __shfl_down(lsum, off, 64);
        lsq  += __shfl_down(lsq,  off, 64);
    }
    if ((tid & 63) == 0) red[tid >> 6] = make_float2(lsum, lsq);
    __syncthreads();
    if (tid == 0) {
        const float s = red[0].x + red[1].x + red[2].x + red[3].x;
        const float q = red[0].y + red[1].y + red[2].y + red[3].y;
        part[c * 12 + b * 3 + blockIdx.x] = make_float2(s, q);
    }

    if (COOP) {
        cg::this_grid().sync();

        // per-channel stats from 12 partials (L2-hot)
        if (tid < 64) {
            float s = 0.0f, q = 0.0f;
            if (tid < 12) {
                const float2 pp = part[c * 12 + tid];
                s = pp.x; q = pp.y;
            }
#pragma unroll
            for (int off = 8; off; off >>= 1) {
                s += __shfl_down(s, off, 64);
                q += __shfl_down(q, off, 64);
            }
            if (tid == 0) {
                const float inv = 1.0f / (float)NPC;
                const float mean = s * inv;
                const float var  = q * inv - mean * mean;
                const float scl  = rsqrtf(var + 1e-5f) * gamma[c];
                sb = make_float2(scl, beta[c] - mean * scl);
            }
        }
        __syncthreads();
        const float2 sbv = sb;

        float* ypl = y + (size_t)plane * PLANE + (size_t)h0 * WW;
#pragma unroll
        for (int wt = 0; wt < TPL; ++wt)
#pragma unroll
            for (int k = 0; k < 4; ++k) {
                const float o = fmaxf(fmaf(acc[wt][k], sbv.x, sbv.y), 0.0f);
                ypl[(ty4 + k) * WW + wt * TILE + tx] = o;
            }
    } else {
        // fallback: write pre-BN y; stage2 normalizes
        float* ypl = y + (size_t)plane * PLANE + (size_t)h0 * WW;
#pragma unroll
        for (int wt = 0; wt < TPL; ++wt)
#pragma unroll
            for (int k = 0; k < 4; ++k)
                ypl[(ty4 + k) * WW + wt * TILE + tx] = acc[wt][k];
    }
}

__global__ __launch_bounds__(BLOCK) void kconv_bn(
    float* __restrict__ y,
    const float2* __restrict__ part,
    const float* __restrict__ gamma,
    const float* __restrict__ beta)
{
    __shared__ float2 sb;
    const int tid = threadIdx.x;
    const int plane = blockIdx.x;
    const int c = plane & (CC - 1);

    if (tid < 64) {
        float s = 0.0f, q = 0.0f;
        if (tid < 12) {
            const float2 pp = part[c * 12 + tid];
            s = pp.x; q = pp.y;
        }
#pragma unroll
        for (int off = 8; off; off >>= 1) {
            s += __shfl_down(s, off, 64);
            q += __shfl_down(q, off, 64);
        }
        if (tid == 0) {
            const float inv = 1.0f / (float)NPC;
            const float mean = s * inv;
            const float var  = q * inv - mean * mean;
            const float sc   = rsqrtf(var + 1e-5f) * gamma[c];
            sb = make_float2(sc, beta[c] - mean * sc);
        }
    }
    __syncthreads();
    const float2 sbv = sb;

    float4* yp = (float4*)(y + (size_t)plane * PLANE + (size_t)blockIdx.y * 1024);
    float4 v = yp[tid];
    v.x = fmaxf(fmaf(v.x, sbv.x, sbv.y), 0.0f);
    v.y = fmaxf(fmaf(v.y, sbv.x, sbv.y), 0.0f);
    v.z = fmaxf(fmaf(v.z, sbv.x, sbv.y), 0.0f);
    v.w = fmaxf(fmaf(v.w, sbv.x, sbv.y), 0.0f);
    yp[tid] = v;
}

extern "C" void kernel_launch(void* const* d_in, const int* in_sizes, int n_in,
                              void* d_out, int out_size, void* d_ws, size_t ws_size,
                              hipStream_t stream)
{
    const float* x        = (const float*)d_in[0];
    const float* base_w   = (const float*)d_in[1];
    const float* spline_w = (const float*)d_in[2];
    const float* spline_s = (const float*)d_in[3];
    const float* gamma    = (const float*)d_in[4];
    const float* beta     = (const float*)d_in[5];
    float* out   = (float*)d_out;
    float2* part = (float2*)d_ws;   // 768 float2; fully written before read

    void* kargs[] = {(void*)&x, (void*)&base_w, (void*)&spline_w, (void*)&spline_s,
                     (void*)&gamma, (void*)&beta, (void*)&out, (void*)&part};
    dim3 g(TPL, NPLANES);           // 768 blocks; coop-capacity >= 1024

    hipError_t err = hipLaunchCooperativeKernel(
        (const void*)(kconv_main<1>), g, dim3(BLOCK), kargs, 0, stream);

    if (err != hipSuccess) {
        (void)hipGetLastError();    // clear; take the two-kernel path
        kconv_main<0><<<g, BLOCK, 0, stream>>>(x, base_w, spline_w, spline_s,
                                               gamma, beta, out, part);
        dim3 g2(NPLANES, PLANE / (BLOCK * 4));
        kconv_bn<<<g2, BLOCK, 0, stream>>>(out, part, gamma, beta);
    }
}

// Round 8
// 85.596 us; speedup vs baseline: 1.7565x; 1.7565x over previous
//
#include <hip/hip_runtime.h>
#include <math.h>

#define HH 96
#define WW 96
#define CC 64
#define BB 4
#define PLANE (HH * WW)          // 9216
#define NPLANES (BB * CC)        // 256
#define NPC (BB * PLANE)         // 36864 per-channel count
#define TILE 32
#define TPL 3
#define NTILES (TPL * TPL)       // 9 (partial slots per plane)
#define HALO 34
#define HALO_N (HALO * HALO)     // 1156
#define BLOCK 256

typedef _Float16 h2v __attribute__((ext_vector_type(2)));

static __device__ __forceinline__ float dot2h(unsigned a, unsigned b, float c) {
#if __has_builtin(__builtin_amdgcn_fdot2)
    return __builtin_amdgcn_fdot2(__builtin_bit_cast(h2v, a),
                                  __builtin_bit_cast(h2v, b), c, false);
#else
    h2v x = __builtin_bit_cast(h2v, a);
    h2v y = __builtin_bit_cast(h2v, b);
    return c + (float)x[0] * (float)y[0] + (float)x[1] * (float)y[1];
#endif
}

static __device__ __forceinline__ unsigned pk16(float a, float b) {
    return __builtin_bit_cast(unsigned, __builtin_amdgcn_cvt_pkrtz(a, b));
}

// Round-3 verified body + LDS double-buffer pipeline:
//   prologue: A(0), B(0)->buf0, barrier
//   iter wt:  A(wt+1) issued early; C(buf[wt&1]) -> y, stats;
//             B(wt+1)->buf[(wt+1)&1]; barrier
// One barrier per tile (was two); phase-A global latency hidden under C.
// 46.4 KB LDS -> 3 blocks/CU, grid = 768 = exactly 3/CU.

__global__ __launch_bounds__(BLOCK) void kconv_stage1(
    const float* __restrict__ x,
    const float* __restrict__ base_w,
    const float* __restrict__ spline_w,   // (9,8)
    const float* __restrict__ spline_s,   // (9,)
    float* __restrict__ y,
    float2* __restrict__ part)
{
    __shared__ uint4  s_n[2][HALO_N];
    __shared__ float  s_sl[2][HALO_N];
    __shared__ unsigned s_wp[36];
    __shared__ float  s_bw[9];
    __shared__ float2 red[4];

    const int tid = threadIdx.x;

    if (tid < 36) {
        const int j = tid >> 2;
        const int k = tid & 3;
        const float sc = spline_s[j];
        s_wp[tid] = pk16(spline_w[j * 8 + 2 * k] * sc,
                         spline_w[j * 8 + 2 * k + 1] * sc);
    }
    if (tid < 9) s_bw[tid] = base_w[tid];

    const int plane = blockIdx.y;
    const int h0 = blockIdx.x * TILE;
    const float* xp = x + (size_t)plane * PLANE;

    int hy[5], hx[5];
#pragma unroll
    for (int s = 0; s < 5; ++s) {
        const int i = tid + s * BLOCK;
        const int r = i / HALO;
        hy[s] = r;
        hx[s] = i - r * HALO;
    }

    const int tx  = tid & 31;
    const int ty4 = (tid >> 5) * 4;

    float lsum = 0.0f, lsq = 0.0f;

    // ---- phase A+B for tile 0 into buf 0 ----
    float v[5];
#pragma unroll
    for (int s = 0; s < 5; ++s) {
        const int gh = h0 + hy[s] - 1;
        const int gw = hx[s] - 1;                 // w0 = 0
        const bool ok = (tid + s * BLOCK < HALO_N) &&
                        gh >= 0 && gh < HH && gw >= 0 && gw < WW;
        v[s] = ok ? xp[gh * WW + gw] : 0.0f;
    }
#pragma unroll
    for (int s = 0; s < 5; ++s) {
        const int i = tid + s * BLOCK;
        if (i >= HALO_N) break;
        const float vv = v[s];
        const float e  = __expf(-vv);
        const float sl = vv * __builtin_amdgcn_rcpf(1.0f + e);
        const float sp = fmaf(vv, 2.5f, 2.5f);
        const float tf = floorf(sp);
        const float u  = sp - tf;
        const int   t  = (int)tf;
        const int   m  = t >> 1;
        const bool  odd = (t & 1) != 0;
        const float w1m = 1.0f - u;
        const float u2 = u * u;
        const float u3 = u2 * u;
        const float B0 = w1m * w1m * (w1m * (1.0f / 6.0f));
        const float B3 = u2 * (u * (1.0f / 6.0f));
        const float B1 = fmaf(-u2, 1.0f, fmaf(u3, 0.5f, 2.0f / 3.0f));
        const float B2 = 1.0f - B0 - B1 - B3;
        const unsigned h01 = pk16(B0, B1);
        const unsigned h23 = pk16(B2, B3);
        unsigned n[4];
        unsigned a_prev;
        {
            const int k0 = -1 - m;
            a_prev = (k0 == 0) ? h01 : ((k0 == 1) ? h23 : 0u);
        }
#pragma unroll
        for (int d = 0; d < 4; ++d) {
            const int k0 = d - m;
            const unsigned a_cur = (k0 == 0) ? h01 : ((k0 == 1) ? h23 : 0u);
            const unsigned sh = __builtin_amdgcn_alignbit(a_cur, a_prev, 16);
            n[d] = odd ? sh : a_cur;
            a_prev = a_cur;
        }
        s_n[0][i]  = make_uint4(n[0], n[1], n[2], n[3]);
        s_sl[0][i] = sl;
    }
    __syncthreads();                              // weights + buf0 visible

    unsigned wp[36];
    float bw[9];
#pragma unroll
    for (int q = 0; q < 36; ++q)
        wp[q] = __builtin_amdgcn_readfirstlane(s_wp[q]);
#pragma unroll
    for (int q = 0; q < 9; ++q)
        bw[q] = __int_as_float(__builtin_amdgcn_readfirstlane(__float_as_int(s_bw[q])));

#pragma unroll
    for (int wt = 0; wt < TPL; ++wt) {
        const int cur = wt & 1;
        const int nxt = cur ^ 1;

        // ---- phase A for tile wt+1 (independent; lands during phase C) ----
        if (wt < TPL - 1) {
            const int w0n = (wt + 1) * TILE;
#pragma unroll
            for (int s = 0; s < 5; ++s) {
                const int gh = h0 + hy[s] - 1;
                const int gw = w0n + hx[s] - 1;
                const bool ok = (tid + s * BLOCK < HALO_N) &&
                                gh >= 0 && gh < HH && gw >= 0 && gw < WW;
                v[s] = ok ? xp[gh * WW + gw] : 0.0f;
            }
        }

        // ---- phase C: consume buf[cur] ----
        float acc[4] = {0.0f, 0.0f, 0.0f, 0.0f};
#pragma unroll
        for (int r = 0; r < 6; ++r) {
            const int base = (ty4 + r) * HALO + tx;
            uint4 cn[3];
            float cs[3];
#pragma unroll
            for (int dw = 0; dw < 3; ++dw) {
                cn[dw] = s_n[cur][base + dw];
                cs[dw] = s_sl[cur][base + dw];
            }
#pragma unroll
            for (int k = 0; k < 4; ++k) {
                const int dh = r - k;
                if (dh >= 0 && dh < 3) {
                    float a = acc[k];
#pragma unroll
                    for (int dw = 0; dw < 3; ++dw) {
                        const int j = dh * 3 + dw;
                        a = dot2h(cn[dw].x, wp[j * 4 + 0], a);
                        a = dot2h(cn[dw].y, wp[j * 4 + 1], a);
                        a = dot2h(cn[dw].z, wp[j * 4 + 2], a);
                        a = dot2h(cn[dw].w, wp[j * 4 + 3], a);
                        a = fmaf(bw[j], cs[dw], a);
                    }
                    acc[k] = a;
                }
            }
        }

        // y write + stats for this tile
        float* yp = y + (size_t)plane * PLANE + (size_t)h0 * WW + wt * TILE;
#pragma unroll
        for (int k = 0; k < 4; ++k) {
            yp[(ty4 + k) * WW + tx] = acc[k];
            lsum += acc[k];
            lsq = fmaf(acc[k], acc[k], lsq);
        }

        // ---- phase B: build buf[nxt] from prefetched v ----
        if (wt < TPL - 1) {
#pragma unroll
            for (int s = 0; s < 5; ++s) {
                const int i = tid + s * BLOCK;
                if (i >= HALO_N) break;
                const float vv = v[s];
                const float e  = __expf(-vv);
                const float sl = vv * __builtin_amdgcn_rcpf(1.0f + e);
                const float sp = fmaf(vv, 2.5f, 2.5f);
                const float tf = floorf(sp);
                const float u  = sp - tf;
                const int   t  = (int)tf;
                const int   m  = t >> 1;
                const bool  odd = (t & 1) != 0;
                const float w1m = 1.0f - u;
                const float u2 = u * u;
                const float u3 = u2 * u;
                const float B0 = w1m * w1m * (w1m * (1.0f / 6.0f));
                const float B3 = u2 * (u * (1.0f / 6.0f));
                const float B1 = fmaf(-u2, 1.0f, fmaf(u3, 0.5f, 2.0f / 3.0f));
                const float B2 = 1.0f - B0 - B1 - B3;
                const unsigned h01 = pk16(B0, B1);
                const unsigned h23 = pk16(B2, B3);
                unsigned n[4];
                unsigned a_prev;
                {
                    const int k0 = -1 - m;
                    a_prev = (k0 == 0) ? h01 : ((k0 == 1) ? h23 : 0u);
                }
#pragma unroll
                for (int d = 0; d < 4; ++d) {
                    const int k0 = d - m;
                    const unsigned a_cur = (k0 == 0) ? h01 : ((k0 == 1) ? h23 : 0u);
                    const unsigned sh = __builtin_amdgcn_alignbit(a_cur, a_prev, 16);
                    n[d] = odd ? sh : a_cur;
                    a_prev = a_cur;
                }
                s_n[nxt][i]  = make_uint4(n[0], n[1], n[2], n[3]);
                s_sl[nxt][i] = sl;
            }
            __syncthreads();                      // one barrier per tile
        }
    }

#pragma unroll
    for (int off = 32; off; off >>= 1) {
        lsum += __shfl_down(lsum, off, 64);
        lsq  += __shfl_down(lsq,  off, 64);
    }
    if ((tid & 63) == 0) red[tid >> 6] = make_float2(lsum, lsq);
    __syncthreads();
    if (tid == 0) {
        const float s = red[0].x + red[1].x + red[2].x + red[3].x;
        const float q = red[0].y + red[1].y + red[2].y + red[3].y;
        part[plane * NTILES + blockIdx.x] = make_float2(s, q);
    }
}

__global__ __launch_bounds__(BLOCK) void kconv_stage2(
    float* __restrict__ y,
    const float2* __restrict__ part,
    const float* __restrict__ gamma,
    const float* __restrict__ beta)
{
    __shared__ float2 sb;
    const int tid = threadIdx.x;
    const int plane = blockIdx.x;
    const int c = plane & (CC - 1);

    if (tid < 64) {
        float s = 0.0f, q = 0.0f;
        if (tid < 12) {                   // 4 batches x 3 strips
            const int b = tid / 3;
            const int t = tid - b * 3;
            const float2 pp = part[(c + CC * b) * NTILES + t];
            s = pp.x; q = pp.y;
        }
#pragma unroll
        for (int off = 8; off; off >>= 1) {
            s += __shfl_down(s, off, 64);
            q += __shfl_down(q, off, 64);
        }
        if (tid == 0) {
            const float inv = 1.0f / (float)NPC;
            const float mean = s * inv;
            const float var  = q * inv - mean * mean;
            const float sc   = rsqrtf(var + 1e-5f) * gamma[c];
            sb = make_float2(sc, beta[c] - mean * sc);
        }
    }
    __syncthreads();
    const float2 sbv = sb;

    float4* yp = (float4*)(y + (size_t)plane * PLANE + (size_t)blockIdx.y * 1024);
    float4 v = yp[tid];
    v.x = fmaxf(fmaf(v.x, sbv.x, sbv.y), 0.0f);
    v.y = fmaxf(fmaf(v.y, sbv.x, sbv.y), 0.0f);
    v.z = fmaxf(fmaf(v.z, sbv.x, sbv.y), 0.0f);
    v.w = fmaxf(fmaf(v.w, sbv.x, sbv.y), 0.0f);
    yp[tid] = v;
}

extern "C" void kernel_launch(void* const* d_in, const int* in_sizes, int n_in,
                              void* d_out, int out_size, void* d_ws, size_t ws_size,
                              hipStream_t stream)
{
    const float* x        = (const float*)d_in[0];
    const float* base_w   = (const float*)d_in[1];
    const float* spline_w = (const float*)d_in[2];
    const float* spline_s = (const float*)d_in[3];
    const float* gamma    = (const float*)d_in[4];
    const float* beta     = (const float*)d_in[5];
    float* out   = (float*)d_out;
    float2* part = (float2*)d_ws;

    dim3 g1(TPL, NPLANES);   // 768 blocks = 3/CU (46.4 KB LDS -> 3 fit)
    kconv_stage1<<<g1, BLOCK, 0, stream>>>(x, base_w, spline_w, spline_s, out, part);

    dim3 g2(NPLANES, PLANE / (BLOCK * 4));
    kconv_stage2<<<g2, BLOCK, 0, stream>>>(out, part, gamma, beta);
}